// Round 3
// baseline (202.452 us; speedup 1.0000x reference)
//
#include <hip/hip_runtime.h>

// SSIM loss: pred/target [16,3,512,512] fp32, 11x11 gaussian (sigma=1.5),
// zero-padded SAME depthwise conv, output scalar 1 - mean(ssim_map).
//
// v3: tile 32x32. Horizontal pass direct from global (register sliding
// window, 4 outputs/lane), hsums stored as 5 scalar LDS planes with
// stride-33 padding (provably conflict-free: <=2 lanes/bank on both write
// and read patterns). Vertical pass streams 14 rows, 4 outputs/thread.
// LDS 27.7 KB -> 5 blocks/CU -> 20 waves/CU (was 3 blocks/12 waves).
// Block-uniform interior fast path drops bounds predicates for 77% of blocks.

#define IMG 512
#define NCHAN 48
#define TW 32
#define TH 32
#define HR (TH + 10)   // 42 hsum rows per tile
#define PST 33         // padded plane row stride (floats)

// exp(-d^2/4.5) raw gaussian values, normalized at compile time
constexpr double RW1 = 0.8007374029168082;   // exp(-1/4.5)
constexpr double RW2 = 0.4111122905071876;   // exp(-4/4.5)
constexpr double RW3 = 0.1353352832366127;   // exp(-9/4.5)
constexpr double RW4 = 0.0285655007845504;   // exp(-16/4.5)
constexpr double RW5 = 0.0038659201394728;   // exp(-25/4.5)
constexpr double RSUM = 1.0 + 2.0 * (RW1 + RW2 + RW3 + RW4 + RW5);
constexpr float GW[11] = {
    (float)(RW5 / RSUM), (float)(RW4 / RSUM), (float)(RW3 / RSUM),
    (float)(RW2 / RSUM), (float)(RW1 / RSUM), (float)(1.0 / RSUM),
    (float)(RW1 / RSUM), (float)(RW2 / RSUM), (float)(RW3 / RSUM),
    (float)(RW4 / RSUM), (float)(RW5 / RSUM)};

template <bool CHECKED>
__device__ __forceinline__ void phase_b(const float* __restrict__ P,
                                        const float* __restrict__ T, int r0t,
                                        int c0, int tid,
                                        float (*hp)[HR][PST]) {
  for (int j = tid; j < HR * 8; j += 256) {
    const int g = j & 7;   // col group (4 outputs)
    const int h = j >> 3;  // hsum row 0..41
    const int x0 = g * 4;
    const int gy = r0t - 5 + h;
    const int gx0 = c0 + x0 - 8;  // aligned 20-float window (mult of 4)
    float pv[20], tv[20];
    if (CHECKED) {
      const bool rowok = (gy >= 0) && (gy < IMG);
      const float* __restrict__ Prow = P + (size_t)gy * IMG;
      const float* __restrict__ Trow = T + (size_t)gy * IMG;
#pragma unroll
      for (int q = 0; q < 5; ++q) {
        const int gx = gx0 + q * 4;
        float4 vp = make_float4(0.f, 0.f, 0.f, 0.f);
        float4 vt = vp;
        // gx is a multiple of 4 and IMG%4==0: float4 is all-in or all-out.
        if (rowok && gx >= 0 && gx < IMG) {
          vp = *(const float4*)(Prow + gx);
          vt = *(const float4*)(Trow + gx);
        }
        pv[q * 4 + 0] = vp.x; pv[q * 4 + 1] = vp.y;
        pv[q * 4 + 2] = vp.z; pv[q * 4 + 3] = vp.w;
        tv[q * 4 + 0] = vt.x; tv[q * 4 + 1] = vt.y;
        tv[q * 4 + 2] = vt.z; tv[q * 4 + 3] = vt.w;
      }
    } else {
      const float* __restrict__ Prow = P + (size_t)gy * IMG + gx0;
      const float* __restrict__ Trow = T + (size_t)gy * IMG + gx0;
#pragma unroll
      for (int q = 0; q < 5; ++q) {
        const float4 vp = *(const float4*)(Prow + q * 4);
        const float4 vt = *(const float4*)(Trow + q * 4);
        pv[q * 4 + 0] = vp.x; pv[q * 4 + 1] = vp.y;
        pv[q * 4 + 2] = vp.z; pv[q * 4 + 3] = vp.w;
        tv[q * 4 + 0] = vt.x; tv[q * 4 + 1] = vt.y;
        tv[q * 4 + 2] = vt.z; tv[q * 4 + 3] = vt.w;
      }
    }
#pragma unroll
    for (int o = 0; o < 4; ++o) {
      float s1 = 0.f, s2 = 0.f, s11 = 0.f, s22 = 0.f, s12 = 0.f;
#pragma unroll
      for (int k = 0; k < 11; ++k) {
        const float p = pv[3 + o + k];
        const float t = tv[3 + o + k];
        const float w = GW[k];
        const float wp = w * p;
        const float wt = w * t;
        s1 += wp;
        s2 += wt;
        s11 += wp * p;
        s22 += wt * t;
        s12 += wp * t;
      }
      hp[0][h][x0 + o] = s1;
      hp[1][h][x0 + o] = s2;
      hp[2][h][x0 + o] = s11;
      hp[3][h][x0 + o] = s22;
      hp[4][h][x0 + o] = s12;
    }
  }
}

__global__ __launch_bounds__(256, 5) void ssim_main(
    const float* __restrict__ pred, const float* __restrict__ tgt,
    double* __restrict__ ws) {
  __shared__ float hp[5][HR][PST];
  __shared__ float wsum[4];

  const int tid = threadIdx.x;
  const int c0 = blockIdx.x * TW;
  const int r0t = blockIdx.y * TH;
  const int nc = blockIdx.z;
  const size_t base = (size_t)nc * IMG * IMG;
  const float* __restrict__ P = pred + base;
  const float* __restrict__ T = tgt + base;

  // ---- Phase B: horizontal windowed sums of {p,t,p2,t2,pt} -> LDS planes
  const bool interior = (c0 != 0) && (c0 != IMG - TW) && (r0t != 0) &&
                        (r0t != IMG - TH);
  if (interior)
    phase_b<false>(P, T, r0t, c0, tid, hp);
  else
    phase_b<true>(P, T, r0t, c0, tid, hp);
  __syncthreads();

  // ---- Phase C: vertical windowed sums, row-streaming, 4 outputs/thread
  float lsum = 0.f;
  {
    const int x = tid & (TW - 1);
    const int r0 = (tid >> 5) * 4;  // 8 groups * 4 rows = 32
    float acc[4][5];
#pragma unroll
    for (int o = 0; o < 4; ++o)
#pragma unroll
      for (int q = 0; q < 5; ++q) acc[o][q] = 0.f;
#pragma unroll
    for (int j = 0; j < 14; ++j) {
      const float h0 = hp[0][r0 + j][x];
      const float h1 = hp[1][r0 + j][x];
      const float h2 = hp[2][r0 + j][x];
      const float h3 = hp[3][r0 + j][x];
      const float h4 = hp[4][r0 + j][x];
#pragma unroll
      for (int o = 0; o < 4; ++o) {
        const int k = j - o;
        if (k >= 0 && k < 11) {
          const float w = GW[k];
          acc[o][0] += w * h0;
          acc[o][1] += w * h1;
          acc[o][2] += w * h2;
          acc[o][3] += w * h3;
          acc[o][4] += w * h4;
        }
      }
    }
#pragma unroll
    for (int o = 0; o < 4; ++o) {
      const float s1 = acc[o][0], s2 = acc[o][1];
      const float s11 = acc[o][2], s22 = acc[o][3], s12 = acc[o][4];
      const float mu11 = s1 * s1;
      const float mu22 = s2 * s2;
      const float mu12 = s1 * s2;
      const float num = (2.f * mu12 + 1e-4f) * (2.f * (s12 - mu12) + 9e-4f);
      const float den =
          (mu11 + mu22 + 1e-4f) * ((s11 - mu11) + (s22 - mu22) + 9e-4f);
      lsum += num * __builtin_amdgcn_rcpf(den);
    }
  }

  // ---- Block reduce, one f64 atomic per block into per-channel bucket
#pragma unroll
  for (int off = 32; off > 0; off >>= 1) lsum += __shfl_down(lsum, off, 64);
  if ((tid & 63) == 0) wsum[tid >> 6] = lsum;
  __syncthreads();
  if (tid == 0) {
    const float bsum = wsum[0] + wsum[1] + wsum[2] + wsum[3];
    unsafeAtomicAdd(&ws[nc], (double)bsum);
  }
}

__global__ void ssim_fin(const double* __restrict__ ws,
                         float* __restrict__ out) {
  const int l = threadIdx.x;
  double v = (l < NCHAN) ? ws[l] : 0.0;
#pragma unroll
  for (int off = 32; off > 0; off >>= 1) v += __shfl_down(v, off, 64);
  if (l == 0) out[0] = (float)(1.0 - v / (double)(IMG * IMG * NCHAN));
}

extern "C" void kernel_launch(void* const* d_in, const int* in_sizes, int n_in,
                              void* d_out, int out_size, void* d_ws,
                              size_t ws_size, hipStream_t stream) {
  const float* pred = (const float*)d_in[0];
  const float* tgt = (const float*)d_in[1];
  double* ws = (double*)d_ws;

  hipMemsetAsync(d_ws, 0, NCHAN * sizeof(double), stream);
  dim3 grid(IMG / TW, IMG / TH, NCHAN);
  ssim_main<<<grid, 256, 0, stream>>>(pred, tgt, ws);
  ssim_fin<<<1, 64, 0, stream>>>(ws, (float*)d_out);
}

// Round 4
// 181.919 us; speedup vs baseline: 1.1129x; 1.1129x over previous
//
#include <hip/hip_runtime.h>

// SSIM loss: pred/target [16,3,512,512] fp32, 11x11 gaussian (sigma=1.5),
// zero-padded SAME depthwise conv, output scalar 1 - mean(ssim_map).
//
// v4: tile 32x64. Horizontal pass direct from global (register sliding
// window, 4 outputs/item, 2-3 items/thread). Hsums in LDS as one float4
// plane (s1,s2,s11,s22) + one scalar plane (s12), both with padded row
// stride 33 -> b128 access is data-limited (8 lanes per 4-bank group),
// no conflict serialization. Vertical pass streams 18 rows with b128+b32
// reads at immediate offsets, 8 outputs/thread.
// LDS 48.9 KB -> 3 blocks/CU. R3 evidence: occupancy beyond 12 waves/CU
// buys ~nothing; instruction volume on VALU+LDS pipes is what matters.

#define IMG 512
#define NCHAN 48
#define TW 32
#define TH 64
#define HR (TH + 10)   // 74 hsum rows per tile
#define PST 33         // padded plane row stride (elements of the plane type)

// exp(-d^2/4.5) raw gaussian values, normalized at compile time
constexpr double RW1 = 0.8007374029168082;   // exp(-1/4.5)
constexpr double RW2 = 0.4111122905071876;   // exp(-4/4.5)
constexpr double RW3 = 0.1353352832366127;   // exp(-9/4.5)
constexpr double RW4 = 0.0285655007845504;   // exp(-16/4.5)
constexpr double RW5 = 0.0038659201394728;   // exp(-25/4.5)
constexpr double RSUM = 1.0 + 2.0 * (RW1 + RW2 + RW3 + RW4 + RW5);
constexpr float GW[11] = {
    (float)(RW5 / RSUM), (float)(RW4 / RSUM), (float)(RW3 / RSUM),
    (float)(RW2 / RSUM), (float)(RW1 / RSUM), (float)(1.0 / RSUM),
    (float)(RW1 / RSUM), (float)(RW2 / RSUM), (float)(RW3 / RSUM),
    (float)(RW4 / RSUM), (float)(RW5 / RSUM)};

// One horizontal item: 4 adjacent hsum outputs on row h from a 20-float
// register window. j in [0, HR*8).
template <bool CHECKED>
__device__ __forceinline__ void hitem(const float* __restrict__ P,
                                      const float* __restrict__ T, int r0t,
                                      int c0, int j, float4 (*hs4)[PST],
                                      float (*hs1)[PST]) {
  const int g = j & 7;   // col group (4 outputs)
  const int h = j >> 3;  // hsum row 0..HR-1
  const int x0 = g * 4;
  const int gy = r0t - 5 + h;
  const int gx0 = c0 + x0 - 8;  // aligned 20-float window (mult of 4)
  float pv[20], tv[20];
  if (CHECKED) {
    const bool rowok = (gy >= 0) && (gy < IMG);
    const float* __restrict__ Prow = P + (size_t)gy * IMG;
    const float* __restrict__ Trow = T + (size_t)gy * IMG;
#pragma unroll
    for (int q = 0; q < 5; ++q) {
      const int gx = gx0 + q * 4;
      float4 vp = make_float4(0.f, 0.f, 0.f, 0.f);
      float4 vt = vp;
      // gx is a multiple of 4 and IMG%4==0: float4 is all-in or all-out.
      if (rowok && gx >= 0 && gx < IMG) {
        vp = *(const float4*)(Prow + gx);
        vt = *(const float4*)(Trow + gx);
      }
      pv[q * 4 + 0] = vp.x; pv[q * 4 + 1] = vp.y;
      pv[q * 4 + 2] = vp.z; pv[q * 4 + 3] = vp.w;
      tv[q * 4 + 0] = vt.x; tv[q * 4 + 1] = vt.y;
      tv[q * 4 + 2] = vt.z; tv[q * 4 + 3] = vt.w;
    }
  } else {
    const float* __restrict__ Prow = P + (size_t)gy * IMG + gx0;
    const float* __restrict__ Trow = T + (size_t)gy * IMG + gx0;
#pragma unroll
    for (int q = 0; q < 5; ++q) {
      const float4 vp = *(const float4*)(Prow + q * 4);
      const float4 vt = *(const float4*)(Trow + q * 4);
      pv[q * 4 + 0] = vp.x; pv[q * 4 + 1] = vp.y;
      pv[q * 4 + 2] = vp.z; pv[q * 4 + 3] = vp.w;
      tv[q * 4 + 0] = vt.x; tv[q * 4 + 1] = vt.y;
      tv[q * 4 + 2] = vt.z; tv[q * 4 + 3] = vt.w;
    }
  }
#pragma unroll
  for (int o = 0; o < 4; ++o) {
    float s1 = 0.f, s2 = 0.f, s11 = 0.f, s22 = 0.f, s12 = 0.f;
#pragma unroll
    for (int k = 0; k < 11; ++k) {
      const float p = pv[3 + o + k];
      const float t = tv[3 + o + k];
      const float w = GW[k];
      const float wp = w * p;
      const float wt = w * t;
      s1 += wp;
      s2 += wt;
      s11 += wp * p;
      s22 += wt * t;
      s12 += wp * t;
    }
    hs4[h][x0 + o] = make_float4(s1, s2, s11, s22);
    hs1[h][x0 + o] = s12;
  }
}

template <bool CHECKED>
__device__ __forceinline__ void phase_b(const float* __restrict__ P,
                                        const float* __restrict__ T, int r0t,
                                        int c0, int tid, float4 (*hs4)[PST],
                                        float (*hs1)[PST]) {
  // HR*8 = 592 items: j = tid and tid+256 unconditional, tid+512 for tid<80.
  hitem<CHECKED>(P, T, r0t, c0, tid, hs4, hs1);
  hitem<CHECKED>(P, T, r0t, c0, tid + 256, hs4, hs1);
  if (tid < HR * 8 - 512) hitem<CHECKED>(P, T, r0t, c0, tid + 512, hs4, hs1);
}

__global__ __launch_bounds__(256, 3) void ssim_main(
    const float* __restrict__ pred, const float* __restrict__ tgt,
    double* __restrict__ ws) {
  __shared__ float4 hs4[HR][PST];  // s1, s2, s11, s22
  __shared__ float hs1[HR][PST];   // s12
  __shared__ float wsum[4];

  const int tid = threadIdx.x;
  const int c0 = blockIdx.x * TW;
  const int r0t = blockIdx.y * TH;
  const int nc = blockIdx.z;
  const size_t base = (size_t)nc * IMG * IMG;
  const float* __restrict__ P = pred + base;
  const float* __restrict__ T = tgt + base;

  // ---- Phase B: horizontal windowed sums of {p,t,p2,t2,pt} -> LDS planes
  const bool interior =
      (c0 != 0) && (c0 != IMG - TW) && (r0t != 0) && (r0t != IMG - TH);
  if (interior)
    phase_b<false>(P, T, r0t, c0, tid, hs4, hs1);
  else
    phase_b<true>(P, T, r0t, c0, tid, hs4, hs1);
  __syncthreads();

  // ---- Phase C: vertical windowed sums, row-streaming, 8 outputs/thread
  float lsum = 0.f;
  {
    const int x = tid & (TW - 1);
    const int r0 = (tid >> 5) * 8;  // 8 strips * 8 rows = 64
    float acc[8][5];
#pragma unroll
    for (int o = 0; o < 8; ++o)
#pragma unroll
      for (int q = 0; q < 5; ++q) acc[o][q] = 0.f;
#pragma unroll
    for (int j = 0; j < 18; ++j) {
      const float4 h4 = hs4[r0 + j][x];
      const float h1 = hs1[r0 + j][x];
#pragma unroll
      for (int o = 0; o < 8; ++o) {
        const int k = j - o;
        if (k >= 0 && k < 11) {
          const float w = GW[k];
          acc[o][0] += w * h4.x;
          acc[o][1] += w * h4.y;
          acc[o][2] += w * h4.z;
          acc[o][3] += w * h4.w;
          acc[o][4] += w * h1;
        }
      }
    }
#pragma unroll
    for (int o = 0; o < 8; ++o) {
      const float s1 = acc[o][0], s2 = acc[o][1];
      const float s11 = acc[o][2], s22 = acc[o][3], s12 = acc[o][4];
      const float mu11 = s1 * s1;
      const float mu22 = s2 * s2;
      const float mu12 = s1 * s2;
      const float num = (2.f * mu12 + 1e-4f) * (2.f * (s12 - mu12) + 9e-4f);
      const float den =
          (mu11 + mu22 + 1e-4f) * ((s11 - mu11) + (s22 - mu22) + 9e-4f);
      lsum += num * __builtin_amdgcn_rcpf(den);
    }
  }

  // ---- Block reduce, one f64 atomic per block into per-channel bucket
#pragma unroll
  for (int off = 32; off > 0; off >>= 1) lsum += __shfl_down(lsum, off, 64);
  if ((tid & 63) == 0) wsum[tid >> 6] = lsum;
  __syncthreads();
  if (tid == 0) {
    const float bsum = wsum[0] + wsum[1] + wsum[2] + wsum[3];
    unsafeAtomicAdd(&ws[nc], (double)bsum);
  }
}

__global__ void ssim_fin(const double* __restrict__ ws,
                         float* __restrict__ out) {
  const int l = threadIdx.x;
  double v = (l < NCHAN) ? ws[l] : 0.0;
#pragma unroll
  for (int off = 32; off > 0; off >>= 1) v += __shfl_down(v, off, 64);
  if (l == 0) out[0] = (float)(1.0 - v / (double)(IMG * IMG * NCHAN));
}

extern "C" void kernel_launch(void* const* d_in, const int* in_sizes, int n_in,
                              void* d_out, int out_size, void* d_ws,
                              size_t ws_size, hipStream_t stream) {
  const float* pred = (const float*)d_in[0];
  const float* tgt = (const float*)d_in[1];
  double* ws = (double*)d_ws;

  hipMemsetAsync(d_ws, 0, NCHAN * sizeof(double), stream);
  dim3 grid(IMG / TW, IMG / TH, NCHAN);
  ssim_main<<<grid, 256, 0, stream>>>(pred, tgt, ws);
  ssim_fin<<<1, 64, 0, stream>>>(ws, (float*)d_out);
}

// Round 5
// 180.974 us; speedup vs baseline: 1.1187x; 1.0052x over previous
//
#include <hip/hip_runtime.h>

// SSIM loss: pred/target [16,3,512,512] fp32, 11x11 gaussian (sigma=1.5),
// zero-padded SAME depthwise conv, output scalar 1 - mean(ssim_map).
//
// v5: v4 structure (tile 32x64, horizontal pass direct from global, hsum
// planes in LDS, vertical row-streaming) + packed-fp32 accumulation:
// the 5 chains pair as (s1,s2) over {p,t}, (s11,s22) over {p2,t2}, s12
// scalar over {p*t}, with per-item shared square/cross precompute.
// Goal: v_pk_fma_f32 halves VALU issue slots on the dominant pipe.
// LDS 48.9 KB -> 3 blocks/CU (12 waves). Known: b128 phase-C reads log
// ~5.5M "conflict" cycles but are data-limited (8 cyc/KB floor), not waste.

#define IMG 512
#define NCHAN 48
#define TW 32
#define TH 64
#define HR (TH + 10)   // 74 hsum rows per tile
#define PST 33         // padded plane row stride

// exp(-d^2/4.5) raw gaussian values, normalized at compile time
constexpr double RW1 = 0.8007374029168082;
constexpr double RW2 = 0.4111122905071876;
constexpr double RW3 = 0.1353352832366127;
constexpr double RW4 = 0.0285655007845504;
constexpr double RW5 = 0.0038659201394728;
constexpr double RSUM = 1.0 + 2.0 * (RW1 + RW2 + RW3 + RW4 + RW5);
constexpr float GW[11] = {
    (float)(RW5 / RSUM), (float)(RW4 / RSUM), (float)(RW3 / RSUM),
    (float)(RW2 / RSUM), (float)(RW1 / RSUM), (float)(1.0 / RSUM),
    (float)(RW1 / RSUM), (float)(RW2 / RSUM), (float)(RW3 / RSUM),
    (float)(RW4 / RSUM), (float)(RW5 / RSUM)};

__device__ __forceinline__ float2 pk_fma(float w, float2 a, float2 c) {
  return make_float2(fmaf(w, a.x, c.x), fmaf(w, a.y, c.y));
}
__device__ __forceinline__ float2 pk_mul(float2 a, float2 b) {
  return make_float2(a.x * b.x, a.y * b.y);
}

// One horizontal item: 4 adjacent hsum outputs on row h from a 20-elem
// register window. j in [0, HR*8).
template <bool CHECKED>
__device__ __forceinline__ void hitem(const float* __restrict__ P,
                                      const float* __restrict__ T, int r0t,
                                      int c0, int j, float4 (*hs4)[PST],
                                      float (*hs1)[PST]) {
  const int g = j & 7;   // col group (4 outputs)
  const int h = j >> 3;  // hsum row 0..HR-1
  const int x0 = g * 4;
  const int gy = r0t - 5 + h;
  const int gx0 = c0 + x0 - 8;  // aligned 20-float window (mult of 4)
  float2 pt[20];   // {p, t}
  if (CHECKED) {
    const bool rowok = (gy >= 0) && (gy < IMG);
    const float* __restrict__ Prow = P + (size_t)gy * IMG;
    const float* __restrict__ Trow = T + (size_t)gy * IMG;
#pragma unroll
    for (int q = 0; q < 5; ++q) {
      const int gx = gx0 + q * 4;
      float4 vp = make_float4(0.f, 0.f, 0.f, 0.f);
      float4 vt = vp;
      // gx is a multiple of 4 and IMG%4==0: float4 is all-in or all-out.
      if (rowok && gx >= 0 && gx < IMG) {
        vp = *(const float4*)(Prow + gx);
        vt = *(const float4*)(Trow + gx);
      }
      pt[q * 4 + 0] = make_float2(vp.x, vt.x);
      pt[q * 4 + 1] = make_float2(vp.y, vt.y);
      pt[q * 4 + 2] = make_float2(vp.z, vt.z);
      pt[q * 4 + 3] = make_float2(vp.w, vt.w);
    }
  } else {
    const float* __restrict__ Prow = P + (size_t)gy * IMG + gx0;
    const float* __restrict__ Trow = T + (size_t)gy * IMG + gx0;
#pragma unroll
    for (int q = 0; q < 5; ++q) {
      const float4 vp = *(const float4*)(Prow + q * 4);
      const float4 vt = *(const float4*)(Trow + q * 4);
      pt[q * 4 + 0] = make_float2(vp.x, vt.x);
      pt[q * 4 + 1] = make_float2(vp.y, vt.y);
      pt[q * 4 + 2] = make_float2(vp.z, vt.z);
      pt[q * 4 + 3] = make_float2(vp.w, vt.w);
    }
  }
  // Shared precompute: squares (packed) and cross products (scalar).
  float2 ptsq[20];
  float ptc[20];
#pragma unroll
  for (int i = 0; i < 20; ++i) {
    ptsq[i] = pk_mul(pt[i], pt[i]);
    ptc[i] = pt[i].x * pt[i].y;
  }
#pragma unroll
  for (int o = 0; o < 4; ++o) {
    float2 smu = make_float2(0.f, 0.f);   // (s1, s2)
    float2 ssq = make_float2(0.f, 0.f);   // (s11, s22)
    float s12 = 0.f;
#pragma unroll
    for (int k = 0; k < 11; ++k) {
      const int i = 3 + o + k;
      const float w = GW[k];
      smu = pk_fma(w, pt[i], smu);
      ssq = pk_fma(w, ptsq[i], ssq);
      s12 = fmaf(w, ptc[i], s12);
    }
    hs4[h][x0 + o] = make_float4(smu.x, smu.y, ssq.x, ssq.y);
    hs1[h][x0 + o] = s12;
  }
}

template <bool CHECKED>
__device__ __forceinline__ void phase_b(const float* __restrict__ P,
                                        const float* __restrict__ T, int r0t,
                                        int c0, int tid, float4 (*hs4)[PST],
                                        float (*hs1)[PST]) {
  // HR*8 = 592 items: j = tid and tid+256 unconditional, tid+512 for tid<80.
  hitem<CHECKED>(P, T, r0t, c0, tid, hs4, hs1);
  hitem<CHECKED>(P, T, r0t, c0, tid + 256, hs4, hs1);
  if (tid < HR * 8 - 512) hitem<CHECKED>(P, T, r0t, c0, tid + 512, hs4, hs1);
}

__global__ __launch_bounds__(256, 3) void ssim_main(
    const float* __restrict__ pred, const float* __restrict__ tgt,
    double* __restrict__ ws) {
  __shared__ float4 hs4[HR][PST];  // s1, s2, s11, s22
  __shared__ float hs1[HR][PST];   // s12
  __shared__ float wsum[4];

  const int tid = threadIdx.x;
  const int c0 = blockIdx.x * TW;
  const int r0t = blockIdx.y * TH;
  const int nc = blockIdx.z;
  const size_t base = (size_t)nc * IMG * IMG;
  const float* __restrict__ P = pred + base;
  const float* __restrict__ T = tgt + base;

  // ---- Phase B: horizontal windowed sums of {p,t,p2,t2,pt} -> LDS planes
  const bool interior =
      (c0 != 0) && (c0 != IMG - TW) && (r0t != 0) && (r0t != IMG - TH);
  if (interior)
    phase_b<false>(P, T, r0t, c0, tid, hs4, hs1);
  else
    phase_b<true>(P, T, r0t, c0, tid, hs4, hs1);
  __syncthreads();

  // ---- Phase C: vertical windowed sums, row-streaming, 8 outputs/thread
  float lsum = 0.f;
  {
    const int x = tid & (TW - 1);
    const int r0 = (tid >> 5) * 8;  // 8 strips * 8 rows = 64
    float2 amu[8], asq[8];
    float a12[8];
#pragma unroll
    for (int o = 0; o < 8; ++o) {
      amu[o] = make_float2(0.f, 0.f);
      asq[o] = make_float2(0.f, 0.f);
      a12[o] = 0.f;
    }
#pragma unroll
    for (int j = 0; j < 18; ++j) {
      const float4 h4 = hs4[r0 + j][x];
      const float h1 = hs1[r0 + j][x];
      const float2 hmu = make_float2(h4.x, h4.y);
      const float2 hsq = make_float2(h4.z, h4.w);
#pragma unroll
      for (int o = 0; o < 8; ++o) {
        const int k = j - o;
        if (k >= 0 && k < 11) {
          const float w = GW[k];
          amu[o] = pk_fma(w, hmu, amu[o]);
          asq[o] = pk_fma(w, hsq, asq[o]);
          a12[o] = fmaf(w, h1, a12[o]);
        }
      }
    }
#pragma unroll
    for (int o = 0; o < 8; ++o) {
      const float s1 = amu[o].x, s2 = amu[o].y;
      const float s11 = asq[o].x, s22 = asq[o].y, s12 = a12[o];
      const float mu11 = s1 * s1;
      const float mu22 = s2 * s2;
      const float mu12 = s1 * s2;
      const float num = (2.f * mu12 + 1e-4f) * (2.f * (s12 - mu12) + 9e-4f);
      const float den =
          (mu11 + mu22 + 1e-4f) * ((s11 - mu11) + (s22 - mu22) + 9e-4f);
      lsum += num * __builtin_amdgcn_rcpf(den);
    }
  }

  // ---- Block reduce, one f64 atomic per block into per-channel bucket
#pragma unroll
  for (int off = 32; off > 0; off >>= 1) lsum += __shfl_down(lsum, off, 64);
  if ((tid & 63) == 0) wsum[tid >> 6] = lsum;
  __syncthreads();
  if (tid == 0) {
    const float bsum = wsum[0] + wsum[1] + wsum[2] + wsum[3];
    unsafeAtomicAdd(&ws[nc], (double)bsum);
  }
}

__global__ void ssim_fin(const double* __restrict__ ws,
                         float* __restrict__ out) {
  const int l = threadIdx.x;
  double v = (l < NCHAN) ? ws[l] : 0.0;
#pragma unroll
  for (int off = 32; off > 0; off >>= 1) v += __shfl_down(v, off, 64);
  if (l == 0) out[0] = (float)(1.0 - v / (double)(IMG * IMG * NCHAN));
}

extern "C" void kernel_launch(void* const* d_in, const int* in_sizes, int n_in,
                              void* d_out, int out_size, void* d_ws,
                              size_t ws_size, hipStream_t stream) {
  const float* pred = (const float*)d_in[0];
  const float* tgt = (const float*)d_in[1];
  double* ws = (double*)d_ws;

  hipMemsetAsync(d_ws, 0, NCHAN * sizeof(double), stream);
  dim3 grid(IMG / TW, IMG / TH, NCHAN);
  ssim_main<<<grid, 256, 0, stream>>>(pred, tgt, ws);
  ssim_fin<<<1, 64, 0, stream>>>(ws, (float*)d_out);
}

// Round 6
// 158.091 us; speedup vs baseline: 1.2806x; 1.1447x over previous
//
#include <hip/hip_runtime.h>

// SSIM loss: pred/target [16,3,512,512] fp32, 11x11 gaussian (sigma=1.5),
// zero-padded SAME depthwise conv, output scalar 1 - mean(ssim_map).
//
// v6: algebraic reduction. With u=p+t, v=p-t the five convs collapse to
// four: cu=conv(u), cv=conv(v), cu2=conv(u^2), cv2=conv(v^2):
//   mu1*mu2       = (cu^2 - cv^2)/4     mu1^2+mu2^2 = (cu^2 + cv^2)/2
//   s12           = (cu2 - cv2)/4       s11+s22     = (cu2 + cv2)/2
// which are exactly the SSIM ingredients. Chains pair as (cu,cv) and
// (cu2,cv2) float2s -> packed-friendly, no scalar leftover.
// One float4 LDS plane (39.1 KB) -> 4 blocks/CU (16 waves, was 12).
// Phase B hoists both unconditional items' global loads before compute.

#define IMG 512
#define NCHAN 48
#define TW 32
#define TH 64
#define HR (TH + 10)   // 74 hsum rows per tile
#define PST 33         // padded plane row stride (float4s)

constexpr double RW1 = 0.8007374029168082;
constexpr double RW2 = 0.4111122905071876;
constexpr double RW3 = 0.1353352832366127;
constexpr double RW4 = 0.0285655007845504;
constexpr double RW5 = 0.0038659201394728;
constexpr double RSUM = 1.0 + 2.0 * (RW1 + RW2 + RW3 + RW4 + RW5);
constexpr float GW[11] = {
    (float)(RW5 / RSUM), (float)(RW4 / RSUM), (float)(RW3 / RSUM),
    (float)(RW2 / RSUM), (float)(RW1 / RSUM), (float)(1.0 / RSUM),
    (float)(RW1 / RSUM), (float)(RW2 / RSUM), (float)(RW3 / RSUM),
    (float)(RW4 / RSUM), (float)(RW5 / RSUM)};

__device__ __forceinline__ float2 pk_scale(float w, float2 a) {
  return make_float2(w * a.x, w * a.y);
}
__device__ __forceinline__ float2 pk_add(float2 a, float2 b) {
  return make_float2(a.x + b.x, a.y + b.y);
}
__device__ __forceinline__ float2 pk_fma2(float2 a, float2 b, float2 c) {
  return make_float2(fmaf(a.x, b.x, c.x), fmaf(a.y, b.y, c.y));
}

// ---- Phase B building blocks: item j in [0, HR*8) = 4 hsum outputs.
template <bool CHECKED>
__device__ __forceinline__ void hload(const float* __restrict__ P,
                                      const float* __restrict__ T, int r0t,
                                      int c0, int j, float4* vp, float4* vt) {
  const int g = j & 7;
  const int h = j >> 3;
  const int gy = r0t - 5 + h;
  const int gx0 = c0 + g * 4 - 8;  // aligned 20-float window (mult of 4)
  if (CHECKED) {
    const bool rowok = (gy >= 0) && (gy < IMG);
    const float* __restrict__ Prow = P + (size_t)gy * IMG;
    const float* __restrict__ Trow = T + (size_t)gy * IMG;
#pragma unroll
    for (int q = 0; q < 5; ++q) {
      const int gx = gx0 + q * 4;
      vp[q] = make_float4(0.f, 0.f, 0.f, 0.f);
      vt[q] = vp[q];
      // gx is a multiple of 4 and IMG%4==0: float4 is all-in or all-out.
      if (rowok && gx >= 0 && gx < IMG) {
        vp[q] = *(const float4*)(Prow + gx);
        vt[q] = *(const float4*)(Trow + gx);
      }
    }
  } else {
    const float* __restrict__ Prow = P + (size_t)gy * IMG + gx0;
    const float* __restrict__ Trow = T + (size_t)gy * IMG + gx0;
#pragma unroll
    for (int q = 0; q < 5; ++q) {
      vp[q] = *(const float4*)(Prow + q * 4);
      vt[q] = *(const float4*)(Trow + q * 4);
    }
  }
}

__device__ __forceinline__ void hcompute(int j, const float4* vp,
                                         const float4* vt,
                                         float4 (*hs)[PST]) {
  const int g = j & 7;
  const int h = j >> 3;
  float2 uv[20];  // (u, v) = (p+t, p-t)
#pragma unroll
  for (int q = 0; q < 5; ++q) {
    const float4 p4 = vp[q], t4 = vt[q];
    uv[q * 4 + 0] = make_float2(p4.x + t4.x, p4.x - t4.x);
    uv[q * 4 + 1] = make_float2(p4.y + t4.y, p4.y - t4.y);
    uv[q * 4 + 2] = make_float2(p4.z + t4.z, p4.z - t4.z);
    uv[q * 4 + 3] = make_float2(p4.w + t4.w, p4.w - t4.w);
  }
#pragma unroll
  for (int o = 0; o < 4; ++o) {
    float2 amu = make_float2(0.f, 0.f);  // (cu, cv)
    float2 asq = make_float2(0.f, 0.f);  // (cu2, cv2)
#pragma unroll
    for (int k = 0; k < 11; ++k) {
      const float2 e = uv[3 + o + k];
      const float2 t1 = pk_scale(GW[k], e);  // (w*u, w*v)
      amu = pk_add(amu, t1);
      asq = pk_fma2(t1, e, asq);             // += (w*u*u, w*v*v)
    }
    hs[h][g * 4 + o] = make_float4(amu.x, amu.y, asq.x, asq.y);
  }
}

template <bool CHECKED>
__device__ __forceinline__ void phase_b(const float* __restrict__ P,
                                        const float* __restrict__ T, int r0t,
                                        int c0, int tid, float4 (*hs)[PST]) {
  // HR*8 = 592 items: tid and tid+256 unconditional (loads hoisted so both
  // items' 20 b128 loads are in flight together), tid+512 for tid<80.
  float4 ap[5], at[5], bp[5], bt[5];
  hload<CHECKED>(P, T, r0t, c0, tid, ap, at);
  hload<CHECKED>(P, T, r0t, c0, tid + 256, bp, bt);
  hcompute(tid, ap, at, hs);
  hcompute(tid + 256, bp, bt, hs);
  if (tid < HR * 8 - 512) {
    hload<CHECKED>(P, T, r0t, c0, tid + 512, ap, at);
    hcompute(tid + 512, ap, at, hs);
  }
}

__global__ __launch_bounds__(256, 4) void ssim_main(
    const float* __restrict__ pred, const float* __restrict__ tgt,
    double* __restrict__ ws) {
  __shared__ float4 hs[HR][PST];  // (cu, cv, cu2, cv2)
  __shared__ float wsum[4];

  const int tid = threadIdx.x;
  const int c0 = blockIdx.x * TW;
  const int r0t = blockIdx.y * TH;
  const int nc = blockIdx.z;
  const size_t base = (size_t)nc * IMG * IMG;
  const float* __restrict__ P = pred + base;
  const float* __restrict__ T = tgt + base;

  const bool interior =
      (c0 != 0) && (c0 != IMG - TW) && (r0t != 0) && (r0t != IMG - TH);
  if (interior)
    phase_b<false>(P, T, r0t, c0, tid, hs);
  else
    phase_b<true>(P, T, r0t, c0, tid, hs);
  __syncthreads();

  // ---- Phase C: vertical windowed sums, row-streaming, 8 outputs/thread
  float lsum = 0.f;
  {
    const int x = tid & (TW - 1);
    const int r0 = (tid >> 5) * 8;  // 8 strips * 8 rows = 64
    float2 amu[8], asq[8];
#pragma unroll
    for (int o = 0; o < 8; ++o) {
      amu[o] = make_float2(0.f, 0.f);
      asq[o] = make_float2(0.f, 0.f);
    }
#pragma unroll
    for (int j = 0; j < 18; ++j) {
      const float4 h4 = hs[r0 + j][x];
      const float2 hmu = make_float2(h4.x, h4.y);
      const float2 hsq = make_float2(h4.z, h4.w);
#pragma unroll
      for (int o = 0; o < 8; ++o) {
        const int k = j - o;
        if (k >= 0 && k < 11) {
          const float w = GW[k];
          amu[o] = pk_fma2(make_float2(w, w), hmu, amu[o]);
          asq[o] = pk_fma2(make_float2(w, w), hsq, asq[o]);
        }
      }
    }
#pragma unroll
    for (int o = 0; o < 8; ++o) {
      const float cu = amu[o].x, cv = amu[o].y;
      const float cu2 = asq[o].x, cv2 = asq[o].y;
      const float cusq = cu * cu, cvsq = cv * cv;
      const float mu12 = 0.25f * (cusq - cvsq);       // mu1*mu2
      const float musq = 0.5f * (cusq + cvsq);        // mu1^2+mu2^2
      const float s12 = 0.25f * (cu2 - cv2);          // conv(p*t)
      const float ssq = 0.5f * (cu2 + cv2);           // s11+s22
      const float num = (2.f * mu12 + 1e-4f) * (2.f * (s12 - mu12) + 9e-4f);
      const float den = (musq + 1e-4f) * (ssq - musq + 9e-4f);
      lsum += num * __builtin_amdgcn_rcpf(den);
    }
  }

  // ---- Block reduce, one f64 atomic per block into per-channel bucket
#pragma unroll
  for (int off = 32; off > 0; off >>= 1) lsum += __shfl_down(lsum, off, 64);
  if ((tid & 63) == 0) wsum[tid >> 6] = lsum;
  __syncthreads();
  if (tid == 0) {
    const float bsum = wsum[0] + wsum[1] + wsum[2] + wsum[3];
    unsafeAtomicAdd(&ws[nc], (double)bsum);
  }
}

__global__ void ssim_fin(const double* __restrict__ ws,
                         float* __restrict__ out) {
  const int l = threadIdx.x;
  double v = (l < NCHAN) ? ws[l] : 0.0;
#pragma unroll
  for (int off = 32; off > 0; off >>= 1) v += __shfl_down(v, off, 64);
  if (l == 0) out[0] = (float)(1.0 - v / (double)(IMG * IMG * NCHAN));
}

extern "C" void kernel_launch(void* const* d_in, const int* in_sizes, int n_in,
                              void* d_out, int out_size, void* d_ws,
                              size_t ws_size, hipStream_t stream) {
  const float* pred = (const float*)d_in[0];
  const float* tgt = (const float*)d_in[1];
  double* ws = (double*)d_ws;

  hipMemsetAsync(d_ws, 0, NCHAN * sizeof(double), stream);
  dim3 grid(IMG / TW, IMG / TH, NCHAN);
  ssim_main<<<grid, 256, 0, stream>>>(pred, tgt, ws);
  ssim_fin<<<1, 64, 0, stream>>>(ws, (float*)d_out);
}